// Round 2
// baseline (422.156 us; speedup 1.0000x reference)
//
#include <hip/hip_runtime.h>

// AngleEnsemble: von Mises mean-shift over softmaxed bin mixture + tiny MLP.
// R2 layout: 1 wave = 4 batch rows (16 lanes/row, 24 bins/lane, float4 loads).
// - No trig in the hot path: direction kept as (c,s)=(X,Y)*rsqrt(X^2+Y^2);
//   w folded into exp2 argument in log2 domain (all scales cancel on normalize).
// - 4-way accumulator trees (short dependency chains).
// - 4-level intra-16 shfl_xor reductions amortized over 4 rows/wave.
// - Wave-uniform early exit when mean-shift has converged (<3e-6 movement).

constexpr int NBINS = 360;
constexpr int BATCH = 65536;
constexpr int MMIX  = 3;
constexpr float K2E  = 1.4426950408889634f;   // log2(e)
constexpr float KAP2 = 14.426950408889634f;   // KAPPA * log2(e)

__device__ __forceinline__ float g16_sum(float v) {
#pragma unroll
  for (int m = 8; m >= 1; m >>= 1) v += __shfl_xor(v, m, 64);
  return v;
}
__device__ __forceinline__ float g16_max(float v) {
#pragma unroll
  for (int m = 8; m >= 1; m >>= 1) v = fmaxf(v, __shfl_xor(v, m, 64));
  return v;
}
__device__ __forceinline__ float w64_sum(float v) {
#pragma unroll
  for (int m = 32; m >= 1; m >>= 1) v += __shfl_xor(v, m, 64);
  return v;
}

__global__ __launch_bounds__(256) void angle_kernel(
    const float* __restrict__ logits, const float* __restrict__ sinv,
    const float* __restrict__ W1, const float* __restrict__ B1,
    const float* __restrict__ W2, const float* __restrict__ B2,
    float* __restrict__ out)
{
  const int lane = threadIdx.x & 63;
  const int p    = lane & 15;          // lane within 16-lane row group
  const int grp  = lane >> 4;          // which of the 4 rows
  const int wid  = blockIdx.x * (blockDim.x >> 6) + (threadIdx.x >> 6);
  const int nw   = gridDim.x * (blockDim.x >> 6);

  // Per-lane bin tables, pre-scaled by KAPPA*log2(e) (scale cancels).
  // float4 chunk c4 covers bins 4c4..4c4+3. Lane owns c4 = p+16j (j<5) and
  // tail chunk 80+p for p<10 (360 floats = 90 float4 = 16*5 + 10).
  float ksn[24], kcn[24];
#pragma unroll
  for (int j = 0; j < 6; ++j) {
    const int c4     = (j < 5) ? (p + 16 * j) : (80 + p);
    const bool valid = (j < 5) || (p < 10);
#pragma unroll
    for (int t = 0; t < 4; ++t) {
      const int n = 4 * c4 + t;
      const float th = (6.2831855f * (float)n) / 360.0f;  // match jnp f32 path
      float s, c;
      sincosf(th, &s, &c);
      ksn[4 * j + t] = valid ? KAP2 * s : 0.0f;
      kcn[4 * j + t] = valid ? KAP2 * c : 0.0f;
    }
  }

  // MLP weights: lane owns hidden cols {lane, lane+64}.
  float w1a[4], w1b[4];
#pragma unroll
  for (int i = 0; i < 4; ++i) {
    w1a[i] = W1[i * 128 + lane];
    w1b[i] = W1[i * 128 + 64 + lane];
  }
  const float b1a = B1[lane], b1b = B1[lane + 64];
  const float w2a0 = W2[lane * 2 + 0], w2a1 = W2[lane * 2 + 1];
  const float w2b0 = W2[(lane + 64) * 2 + 0], w2b1 = W2[(lane + 64) * 2 + 1];
  const float b20 = B2[0], b21 = B2[1];

  const float4* lg4 = reinterpret_cast<const float4*>(logits);
  const float2* sv2 = reinterpret_cast<const float2*>(sinv);
  float2* out2 = reinterpret_cast<float2*>(out);

  for (int q = wid; q < BATCH / 4; q += nw) {
    const int b = 4 * q + grp;

    float w[24];
#pragma unroll
    for (int k = 0; k < 24; ++k) w[k] = 0.0f;

    // --- softmax over N per mixture component, accumulate mixture weight ---
#pragma unroll
    for (int m = 0; m < MMIX; ++m) {
      const float4* row = lg4 + ((size_t)m * BATCH + b) * (NBINS / 4);
      float lv[24];
#pragma unroll
      for (int j = 0; j < 5; ++j) {
        const float4 v = row[p + 16 * j];
        lv[4 * j] = v.x; lv[4 * j + 1] = v.y; lv[4 * j + 2] = v.z; lv[4 * j + 3] = v.w;
      }
      if (p < 10) {
        const float4 v = row[80 + p];
        lv[20] = v.x; lv[21] = v.y; lv[22] = v.z; lv[23] = v.w;
      } else {
        lv[20] = -1e30f; lv[21] = -1e30f; lv[22] = -1e30f; lv[23] = -1e30f;
      }
      // max (tree) then group-reduce
      float m0 = lv[0], m1 = lv[1], m2 = lv[2], m3 = lv[3];
#pragma unroll
      for (int k = 4; k < 24; k += 4) {
        m0 = fmaxf(m0, lv[k]);     m1 = fmaxf(m1, lv[k + 1]);
        m2 = fmaxf(m2, lv[k + 2]); m3 = fmaxf(m3, lv[k + 3]);
      }
      float mx = g16_max(fmaxf(fmaxf(m0, m1), fmaxf(m2, m3)));
      const float mK = mx * K2E;
      float s0 = 0.f, s1 = 0.f, s2 = 0.f, s3 = 0.f;
#pragma unroll
      for (int k = 0; k < 24; k += 4) {
        lv[k]     = __builtin_amdgcn_exp2f(fmaf(lv[k],     K2E, -mK));
        lv[k + 1] = __builtin_amdgcn_exp2f(fmaf(lv[k + 1], K2E, -mK));
        lv[k + 2] = __builtin_amdgcn_exp2f(fmaf(lv[k + 2], K2E, -mK));
        lv[k + 3] = __builtin_amdgcn_exp2f(fmaf(lv[k + 3], K2E, -mK));
        s0 += lv[k]; s1 += lv[k + 1]; s2 += lv[k + 2]; s3 += lv[k + 3];
      }
      const float ssum = g16_sum((s0 + s1) + (s2 + s3));
      const float rs = __builtin_amdgcn_rcpf(ssum);
#pragma unroll
      for (int k = 0; k < 24; ++k) w[k] = fmaf(lv[k], rs, w[k]);
    }

    // --- init direction (scale-free) ---
    float x0 = 0.f, x1 = 0.f, y0 = 0.f, y1 = 0.f;
#pragma unroll
    for (int k = 0; k < 24; k += 2) {
      x0 = fmaf(w[k], kcn[k], x0); y0 = fmaf(w[k], ksn[k], y0);
      x1 = fmaf(w[k + 1], kcn[k + 1], x1); y1 = fmaf(w[k + 1], ksn[k + 1], y1);
    }
    float X = g16_sum(x0 + x1), Y = g16_sum(y0 + y1);
    float rinv = __builtin_amdgcn_rsqf(fmaf(X, X, Y * Y));
    float c = X * rinv, s = Y * rinv;

    // w -> log2(w) in place (reused for all 10 iterations)
#pragma unroll
    for (int k = 0; k < 24; ++k)
      w[k] = (w[k] > 0.0f) ? __builtin_amdgcn_logf(w[k]) : -1e30f;

    // --- mean-shift iterations, Cartesian, early-exit when converged ---
    for (int it = 0; it < 10; ++it) {
      float a0 = 0.f, a1 = 0.f, a2 = 0.f, a3 = 0.f;
      float b0 = 0.f, b1 = 0.f, b2 = 0.f, b3 = 0.f;
#pragma unroll
      for (int k = 0; k < 24; k += 4) {
        const float e0 = __builtin_amdgcn_exp2f(fmaf(c, kcn[k],     fmaf(s, ksn[k],     w[k])));
        const float e1 = __builtin_amdgcn_exp2f(fmaf(c, kcn[k + 1], fmaf(s, ksn[k + 1], w[k + 1])));
        const float e2 = __builtin_amdgcn_exp2f(fmaf(c, kcn[k + 2], fmaf(s, ksn[k + 2], w[k + 2])));
        const float e3 = __builtin_amdgcn_exp2f(fmaf(c, kcn[k + 3], fmaf(s, ksn[k + 3], w[k + 3])));
        a0 = fmaf(e0, kcn[k], a0);     b0 = fmaf(e0, ksn[k], b0);
        a1 = fmaf(e1, kcn[k + 1], a1); b1 = fmaf(e1, ksn[k + 1], b1);
        a2 = fmaf(e2, kcn[k + 2], a2); b2 = fmaf(e2, ksn[k + 2], b2);
        a3 = fmaf(e3, kcn[k + 3], a3); b3 = fmaf(e3, ksn[k + 3], b3);
      }
      const float nX = g16_sum((a0 + a1) + (a2 + a3));
      const float nY = g16_sum((b0 + b1) + (b2 + b3));
      rinv = __builtin_amdgcn_rsqf(fmaf(nX, nX, nY * nY));
      const float nc = nX * rinv, ns = nY * rinv;
      const float d = fabsf(nc - c) + fabsf(ns - s);
      c = nc; s = ns;
      if (__all(d < 3e-6f)) break;   // all 4 rows converged -> remaining iters no-op
    }

    // --- fused MLP head, full wave per row ---
#pragma unroll
    for (int h = 0; h < 4; ++h) {
      const int bb = 4 * q + h;
      const float cc = __shfl(c, h * 16, 64);
      const float ss = __shfl(s, h * 16, 64);
      const float2 sv = sv2[bb];
      float ha = fmaf(sv.x, w1a[0], fmaf(sv.y, w1a[1],
                 fmaf(cc, w1a[2], fmaf(ss, w1a[3], b1a))));
      float hb = fmaf(sv.x, w1b[0], fmaf(sv.y, w1b[1],
                 fmaf(cc, w1b[2], fmaf(ss, w1b[3], b1b))));
      ha = fmaxf(ha, 0.0f); hb = fmaxf(hb, 0.0f);
      float o0 = fmaf(ha, w2a0, hb * w2b0);
      float o1 = fmaf(ha, w2a1, hb * w2b1);
      o0 = w64_sum(o0); o1 = w64_sum(o1);
      o0 += b20; o1 += b21;
      const float nrm = fmaxf(sqrtf(fmaf(o0, o0, o1 * o1)), 1e-12f);
      const float inv = 1.0f / nrm;
      if (lane == h) out2[bb] = make_float2(o0 * inv, o1 * inv);
    }
  }
}

extern "C" void kernel_launch(void* const* d_in, const int* in_sizes, int n_in,
                              void* d_out, int out_size, void* d_ws, size_t ws_size,
                              hipStream_t stream) {
  const float* logits = (const float*)d_in[0];
  const float* sinv   = (const float*)d_in[1];
  const float* W1     = (const float*)d_in[2];
  const float* B1     = (const float*)d_in[3];
  const float* W2     = (const float*)d_in[4];
  const float* B2     = (const float*)d_in[5];
  float* out = (float*)d_out;
  hipLaunchKernelGGL(angle_kernel, dim3(2048), dim3(256), 0, stream,
                     logits, sinv, W1, B1, W2, B2, out);
}

// Round 5
// 403.743 us; speedup vs baseline: 1.0456x; 1.0456x over previous
//
#include <hip/hip_runtime.h>

// AngleEnsemble R5: re-anchor on R1's PROVEN arithmetic (passed, 399us).
// 1 wave = 2 rows (32 lanes/row, 12 bins/lane, float2 loads), per-lane trig
// tables, max-sub softmax, shfl_xor reductions — byte-exact R1 math.
// Deltas vs R1 (all arithmetic-neutral):
//  - e[] merged into lv[] (same ops, fewer live regs)
//  - MLP weights loaded in epilogue (register-pressure relief)
//  - early exit ONLY on bit-exact fixed point (d==0): provably identical
// POST-MORTEM NOTE (R3/R4): frame-rotation bin algebra + no-max-sub softmax
// caused deterministic mode flips on knife-edge elements (absmax 1.97). Do
// NOT reintroduce; arithmetic must track the reference structure closely.

constexpr int NBINS = 360;
constexpr int BATCH = 65536;
constexpr int MMIX  = 3;
constexpr float K2E  = 1.4426950408889634f;   // log2(e)
constexpr float KAP2 = 14.426950408889634f;   // KAPPA * log2(e)

__device__ __forceinline__ float g32_sum(float v) {
#pragma unroll
  for (int m = 16; m >= 1; m >>= 1) v += __shfl_xor(v, m, 64);
  return v;
}
__device__ __forceinline__ float g32_max(float v) {
#pragma unroll
  for (int m = 16; m >= 1; m >>= 1) v = fmaxf(v, __shfl_xor(v, m, 64));
  return v;
}
__device__ __forceinline__ float w64_sum(float v) {
#pragma unroll
  for (int m = 32; m >= 1; m >>= 1) v += __shfl_xor(v, m, 64);
  return v;
}

__global__ __launch_bounds__(256) void angle_kernel(
    const float* __restrict__ logits, const float* __restrict__ sinv,
    const float* __restrict__ W1, const float* __restrict__ B1,
    const float* __restrict__ W2, const float* __restrict__ B2,
    float* __restrict__ out)
{
  const int lane = threadIdx.x & 63;
  const int p    = lane & 31;          // index within 32-lane group
  const int half = lane >> 5;          // which row of the pair
  const int wid  = blockIdx.x * (blockDim.x >> 6) + (threadIdx.x >> 6);
  const int nw   = gridDim.x * (blockDim.x >> 6);

  // Per-lane bin tables: bins 2*(p+32j)+t for j<5, tail bins 320+2p+t (p<20).
  // Tables pre-scaled by KAPPA*log2(e); scale cancels in normalization.
  float ksn[12], kcn[12];
#pragma unroll
  for (int j = 0; j < 6; ++j) {
    const int chunk  = (j < 5) ? (p + 32 * j) : (160 + p);
    const bool valid = (j < 5) || (p < 20);
#pragma unroll
    for (int t = 0; t < 2; ++t) {
      const int n = 2 * chunk + t;
      const float th = (6.2831855f * (float)n) / 360.0f;  // match jnp f32 path
      float s, c;
      sincosf(th, &s, &c);
      ksn[2 * j + t] = valid ? KAP2 * s : 0.0f;
      kcn[2 * j + t] = valid ? KAP2 * c : 0.0f;
    }
  }

  const float2* lg2 = reinterpret_cast<const float2*>(logits);
  const float2* sv2 = reinterpret_cast<const float2*>(sinv);
  float2* out2 = reinterpret_cast<float2*>(out);

  for (int pr = wid; pr < BATCH / 2; pr += nw) {
    const int b = 2 * pr + half;

    float w[12];
#pragma unroll
    for (int k = 0; k < 12; ++k) w[k] = 0.0f;

    // --- softmax over N per mixture component, accumulate mixture weight ---
#pragma unroll
    for (int m = 0; m < MMIX; ++m) {
      const float2* row = lg2 + ((size_t)m * BATCH + b) * (NBINS / 2);
      float lv[12];
#pragma unroll
      for (int j = 0; j < 5; ++j) {
        const float2 v = row[p + 32 * j];
        lv[2 * j] = v.x; lv[2 * j + 1] = v.y;
      }
      if (p < 20) {
        const float2 v = row[160 + p];
        lv[10] = v.x; lv[11] = v.y;
      } else {
        lv[10] = -1e30f; lv[11] = -1e30f;
      }
      float mx = lv[0];
#pragma unroll
      for (int k = 1; k < 12; ++k) mx = fmaxf(mx, lv[k]);
      mx = g32_max(mx);
      float ssum = 0.0f;
#pragma unroll
      for (int k = 0; k < 12; ++k) {
        lv[k] = __builtin_amdgcn_exp2f((lv[k] - mx) * K2E);
        ssum += lv[k];
      }
      ssum = g32_sum(ssum);
      const float rs = 1.0f / ssum;
#pragma unroll
      for (int k = 0; k < 12; ++k) w[k] = fmaf(lv[k], rs, w[k]);
    }

    // --- init direction: (X,Y) ∝ (w·cos_n, w·sin_n); scale cancels ---
    float X = 0.0f, Y = 0.0f;
#pragma unroll
    for (int k = 0; k < 12; ++k) {
      X = fmaf(w[k], kcn[k], X);
      Y = fmaf(w[k], ksn[k], Y);
    }
    X = g32_sum(X); Y = g32_sum(Y);
    float rinv = __builtin_amdgcn_rsqf(fmaf(X, X, Y * Y));
    float c = X * rinv, s = Y * rinv;

    // log2(w) so the kernel weight folds into one exp2 per bin
    float l2w[12];
#pragma unroll
    for (int k = 0; k < 12; ++k)
      l2w[k] = (w[k] > 0.0f) ? __builtin_amdgcn_logf(w[k]) : -1e30f;

    // --- 10 mean-shift iterations, fully in Cartesian form ---
    for (int it = 0; it < 10; ++it) {
      float nX = 0.0f, nY = 0.0f;
#pragma unroll
      for (int k = 0; k < 12; ++k) {
        const float arg = fmaf(c, kcn[k], fmaf(s, ksn[k], l2w[k]));
        const float ee  = __builtin_amdgcn_exp2f(arg);
        nX = fmaf(ee, kcn[k], nX);
        nY = fmaf(ee, ksn[k], nY);
      }
      nX = g32_sum(nX); nY = g32_sum(nY);
      rinv = __builtin_amdgcn_rsqf(fmaf(nX, nX, nY * nY));
      const float nc = nX * rinv, ns = nY * rinv;
      const float d = fabsf(nc - c) + fabsf(ns - s);
      c = nc; s = ns;
      // Bit-exact fixed point only: skipped iterations provably reproduce
      // the same bits, so this cannot change the result.
      if (__all(d == 0.0f)) break;
    }

    // --- fused MLP head (weights loaded here; cached in L1/L2) ---
    float w1a[4], w1b[4];
#pragma unroll
    for (int i = 0; i < 4; ++i) {
      w1a[i] = W1[i * 128 + lane];
      w1b[i] = W1[i * 128 + 64 + lane];
    }
    const float b1a = B1[lane], b1b = B1[lane + 64];
    const float w2a0 = W2[lane * 2 + 0], w2a1 = W2[lane * 2 + 1];
    const float w2b0 = W2[(lane + 64) * 2 + 0], w2b1 = W2[(lane + 64) * 2 + 1];
    const float b20 = B2[0], b21 = B2[1];

#pragma unroll
    for (int h = 0; h < 2; ++h) {
      const int bb = 2 * pr + h;
      const float cc = __shfl(c, h * 32, 64);
      const float ss = __shfl(s, h * 32, 64);
      const float2 sv = sv2[bb];
      float ha = fmaf(sv.x, w1a[0], fmaf(sv.y, w1a[1],
                 fmaf(cc, w1a[2], fmaf(ss, w1a[3], b1a))));
      float hb = fmaf(sv.x, w1b[0], fmaf(sv.y, w1b[1],
                 fmaf(cc, w1b[2], fmaf(ss, w1b[3], b1b))));
      ha = fmaxf(ha, 0.0f); hb = fmaxf(hb, 0.0f);
      float o0 = fmaf(ha, w2a0, hb * w2b0);
      float o1 = fmaf(ha, w2a1, hb * w2b1);
      o0 = w64_sum(o0); o1 = w64_sum(o1);
      o0 += b20; o1 += b21;
      const float nrm = fmaxf(sqrtf(fmaf(o0, o0, o1 * o1)), 1e-12f);
      const float inv = 1.0f / nrm;
      if (lane == 0) out2[bb] = make_float2(o0 * inv, o1 * inv);
    }
  }
}

extern "C" void kernel_launch(void* const* d_in, const int* in_sizes, int n_in,
                              void* d_out, int out_size, void* d_ws, size_t ws_size,
                              hipStream_t stream) {
  const float* logits = (const float*)d_in[0];
  const float* sinv   = (const float*)d_in[1];
  const float* W1     = (const float*)d_in[2];
  const float* B1     = (const float*)d_in[3];
  const float* W2     = (const float*)d_in[4];
  const float* B2     = (const float*)d_in[5];
  float* out = (float*)d_out;
  hipLaunchKernelGGL(angle_kernel, dim3(2048), dim3(256), 0, stream,
                     logits, sinv, W1, B1, W2, B2, out);
}